// Round 3
// baseline (3374.417 us; speedup 1.0000x reference)
//
#include <hip/hip_runtime.h>

// Problem constants
#define NN 2048
#define DD 128
#define KK 16
#define TT 16
#define EE 8192
#define TWOE 16384
#define CNT 262144.0f   // T * 2E

#define LOG2E 1.4426950408889634f
#define LN2   0.6931471805599453f
#define NBLK  256
#define NTHR  512

__device__ __forceinline__ float exp2_(float x) { return __builtin_amdgcn_exp2f(x); }
__device__ __forceinline__ float log2_(float x) { return __builtin_amdgcn_logf(x); }
__device__ __forceinline__ float expf_(float x) { return exp2_(x * LOG2E); }
__device__ __forceinline__ float logf_(float x) { return log2_(x) * LN2; }
__device__ __forceinline__ float sigmoidf_(float x) { return 1.f / (1.f + expf_(-x)); }
__device__ __forceinline__ float softplusf_(float x) { return fmaxf(x, 0.f) + logf_(1.f + expf_(-fabsf(x))); }
__device__ __forceinline__ float tanhf_(float x) { return 1.f - 2.f / (1.f + expf_(2.f * x)); }

#define D4(a,b) ((a).x*(b).x + (a).y*(b).y + (a).z*(b).z + (a).w*(b).w)
#define ZSTEP(A,B,Wv,Bv) { float4 a_=(A), b_=(B); \
    lp += a_.x*(Bv).x + a_.y*(Bv).y + a_.z*(Bv).z + a_.w*(Bv).w; \
    lq += (a_.x*b_.x)*(Wv).x + (a_.y*b_.y)*(Wv).y + (a_.z*b_.z)*(Wv).z + (a_.w*b_.w)*(Wv).w; }

__global__ void zero_cnt_kernel(unsigned* bcnt) { if (threadIdx.x == 0) *bcnt = 0u; }

// ---------------------------------------------------------------------------
// Persistent mega-kernel: 256 blocks x 512 threads (1 block/CU, co-resident).
// Grid barriers via monotone counter (accv[7]), release-add + relaxed spin +
// single acquire fence (avoids inv-spam from acquire-polling: each agent-
// acquire invalidates this XCD's caches, hurting straggler blocks).
// Phases: P0 init -> P1 phi0 GEMV (+beta chain t=0 on blocks 252..255) ->
//   per t: P23 gru-phi + ms-phi + mt (block-local dep, fused) | B1 |
//          P4 znll (+beta chain t+1 hidden on blocks 252..255) | B2.
// Bg_c / Bms_c stored k-major ([k][row]) so beta_step lane-jj reads coalesce.
// ---------------------------------------------------------------------------
__launch_bounds__(NTHR)
__global__ void mega_kernel(
    const int* __restrict__ edges, const int* __restrict__ sidx,
    const float* __restrict__ eps_phi, const float* __restrict__ eps_beta,
    const float* __restrict__ u_g,
    const float* __restrict__ amE, const float* __restrict__ asE,
    const float* __restrict__ W_s2phi, const float* __restrict__ b_s2phi,
    const float* __restrict__ W_s2beta, const float* __restrict__ b_s2beta,
    const float* __restrict__ W_bmean, const float* __restrict__ b_bmean,
    const float* __restrict__ W_bstd, const float* __restrict__ b_bstd,
    const float* __restrict__ W_pmean, const float* __restrict__ b_pmean,
    const float* __restrict__ W_pstd, const float* __restrict__ b_pstd,
    const float* __restrict__ W_pi,
    const float* __restrict__ Wih_n, const float* __restrict__ Whh_n,
    const float* __restrict__ bih_n, const float* __restrict__ bhh_n,
    const float* __restrict__ Wih_c, const float* __restrict__ Whh_c,
    const float* __restrict__ bih_c, const float* __restrict__ bhh_c,
    const float* __restrict__ W_dec,
    float* Bg_n, float* Bg_c, float* Bms_n, float* Bms_c, float* a_m,
    float* phiA, float* phiB, float* hphiA, float* hphiB,
    float* betaA, float* betaB, float* hbetaA, float* hbetaB,
    float* Mt, float* accv, float* out)
{
    const int bid = blockIdx.x;
    const int tid = threadIdx.x;
    const int wid = tid >> 6;
    const int l   = tid & 63;
    __shared__ __align__(16) float smem[14336];   // 56 KB
    unsigned gen = 0;
    unsigned* bcnt = (unsigned*)(accv + 7);

#define GRIDBAR() do { \
        gen++; __syncthreads(); \
        if (tid == 0) { \
            __hip_atomic_fetch_add(bcnt, 1u, __ATOMIC_RELEASE, __HIP_MEMORY_SCOPE_AGENT); \
            unsigned tgt_ = gen * (unsigned)NBLK; \
            while (__hip_atomic_load(bcnt, __ATOMIC_RELAXED, __HIP_MEMORY_SCOPE_AGENT) < tgt_) \
                __builtin_amdgcn_s_sleep(2); \
            __builtin_amdgcn_fence(__ATOMIC_ACQUIRE, "agent"); \
        } \
        __syncthreads(); \
    } while (0)

    const int rb0 = (bid - 252) * 4;   // beta row base for blocks 252..255

    // ---- beta chain single step (runs on blocks 252..255 only) -------------
    // XgIn == nullptr -> Xl (smem+4096) pre-filled. HgIn == nullptr -> h=0.
    auto beta_step = [&](int ts, const float* XgIn, const float* HgIn,
                         float* bOut, float* hOut) {
        float* Xl  = smem + 4096;   // [4][128]
        float* Hl  = smem + 4608;   // [4][128]
        float* hb  = smem + 5120;   // [3][4][128]
        float* hnb = smem + 6656;   // [4][128]
        float* mb  = smem + 7168;   // [2][4][128]
        float* rd  = smem + 8192;   // [8]
        const int jj = tid & 127;
        if (XgIn) Xl[tid] = XgIn[rb0*128 + tid];
        Hl[tid] = HgIn ? HgIn[rb0*128 + tid] : 0.f;
        __syncthreads();
        // gru: thread = (jj, half, rp) -> 2 rows x 3 gates; Bg_c k-major
        const int half = tid >> 8;
        const int rp   = (tid >> 7) & 1;
        const int lr   = rp * 2;
        float a0[3] = {0.f,0.f,0.f}, a1[3] = {0.f,0.f,0.f};
        {
            const float* src = half ? Hl : Xl;
            const float* s0 = src + lr*128;
            const float* s1 = src + lr*128 + 128;
            const int cb = half*384 + jj;      // column base within 768
            for (int k = 0; k < 128; ++k) {
                float v0 = s0[k], v1 = s1[k];
                const float* wrow = Bg_c + (size_t)k*768 + cb;
                #pragma unroll
                for (int gi = 0; gi < 3; ++gi) {
                    float w = wrow[gi*128];
                    a0[gi] = fmaf(v0, w, a0[gi]);
                    a1[gi] = fmaf(v1, w, a1[gi]);
                }
            }
        }
        if (half == 1) {
            #pragma unroll
            for (int gi = 0; gi < 3; ++gi) {
                float bh = bhh_c[gi*128 + jj];
                hb[(gi*4 + lr  )*128 + jj] = a0[gi] + bh;
                hb[(gi*4 + lr+1)*128 + jj] = a1[gi] + bh;
            }
        }
        __syncthreads();
        if (half == 0) {
            #pragma unroll
            for (int ri = 0; ri < 2; ++ri) {
                int row = lr + ri;
                float ar = ri ? a1[0] : a0[0];
                float az = ri ? a1[1] : a0[1];
                float an = ri ? a1[2] : a0[2];
                float r_ = sigmoidf_(ar + bih_c[jj]       + hb[(0*4+row)*128 + jj]);
                float z_ = sigmoidf_(az + bih_c[128 + jj] + hb[(1*4+row)*128 + jj]);
                float n_ = tanhf_   (an + bih_c[256 + jj] + r_*hb[(2*4+row)*128 + jj]);
                float hold = Hl[row*128 + jj];
                float hv = (1.f - z_)*n_ + z_*hold;
                hOut[(size_t)(rb0+row)*128 + jj] = hv;
                hnb[row*128 + jj] = hv;
            }
        }
        __syncthreads();
        // ms: thread = (jj, q) -> 2 rows x 1 group; Bms_c k-major
        {
            const int q = tid >> 7;          // 0..3
            const int grp = q >> 1;          // 0 mean, 1 std
            const int lr2 = (q & 1) * 2;
            float m0 = 0.f, m1 = 0.f;
            const float* h0 = hnb + lr2*128;
            const float* h1 = h0 + 128;
            const int cb = grp*128 + jj;
            for (int k = 0; k < 128; ++k) {
                float w = Bms_c[(size_t)k*256 + cb];
                m0 = fmaf(h0[k], w, m0);
                m1 = fmaf(h1[k], w, m1);
            }
            float bias = grp ? b_bstd[jj] : b_bmean[jj];
            mb[(grp*4 + lr2  )*128 + jj] = m0 + bias;
            mb[(grp*4 + lr2+1)*128 + jj] = m1 + bias;
        }
        __syncthreads();
        // finalize: sample + KLD (prior = Xl)
        float kld;
        {
            int row = tid >> 7, j2 = tid & 127;
            float mean = mb[row*128 + j2];
            float stdv = softplusf_(mb[(4+row)*128 + j2]);
            size_t gi2 = (size_t)(rb0+row)*128 + j2;
            float outv = mean + stdv * eps_beta[(size_t)ts*2048 + gi2];
            bOut[gi2] = outv;
            float d = mean - Xl[row*128 + j2];
            kld = (-2.3025850929940457f - logf_(stdv)) + 50.0f*(stdv*stdv + d*d) - 0.5f;
        }
        #pragma unroll
        for (int m = 1; m < 64; m <<= 1) kld += __shfl_xor(kld, m);
        if (l == 0) rd[wid] = kld;
        __syncthreads();
        if (tid == 0) {
            float s = 0.f;
            #pragma unroll
            for (int w2 = 0; w2 < 8; ++w2) s += rd[w2];
            atomicAdd(accv + 3, s);
        }
        __syncthreads();
    };

    // ======================= P0: init ========================================
    {
        #pragma unroll 1
        for (int ii = 0; ii < 2; ++ii) {
            int idx = bid*NTHR + tid + ii*131072;   // 0..262143
            if (idx < 98304) {
                int r = idx;
                if (r < 49152) { int j2 = r >> 7, k2 = r & 127; Bg_n[r] = Wih_n[j2*256 + k2] + Wih_n[j2*256 + 128 + k2]; }
                else Bg_n[r] = Whh_n[r - 49152];
            } else if (idx < 196608) {
                int r = idx - 98304;                 // 0..98303
                int row = r >> 7, k2 = r & 127;      // row 0..767
                float v = (r < 49152) ? (Wih_c[row*256 + k2] + Wih_c[row*256 + 128 + k2])
                                      : Whh_c[(row - 384)*128 + k2];
                Bg_c[k2*768 + row] = v;              // k-major
            } else if (idx < 229376) {
                int r = idx - 196608;
                Bms_n[r] = (r < 16384) ? W_pmean[r] : W_pstd[r - 16384];
            } else {
                int r = idx - 229376;                // 0..32767
                float v = (r < 16384) ? W_bmean[r] : W_bstd[r - 16384];
                int rr_ = r & 16383; int row = rr_ >> 7, k2 = rr_ & 127; int grp = r >> 14;
                Bms_c[k2*256 + grp*128 + row] = v;   // k-major
            }
            hphiA[idx] = 0.f;
            if (idx < 7 && idx != 2) accv[idx] = 0.f;   // idx 7 = barrier counter!
        }
        if (bid == 0) {
            float v = 0.f;
            if (tid < 128) {
                int s = sidx[0];
                float am = amE[s*128 + tid];
                float as = softplusf_(asE[s*128 + tid]);
                a_m[tid] = am;
                v = -logf_(as) + 0.5f*(as*as + am*am) - 0.5f;
            }
            #pragma unroll
            for (int m = 1; m < 64; m <<= 1) v += __shfl_xor(v, m);
            if (l == 0) smem[wid] = v;
            __syncthreads();
            if (tid == 0) {
                float s = 0.f;
                #pragma unroll
                for (int w2 = 0; w2 < 8; ++w2) s += smem[w2];
                accv[2] = s;
            }
        }
    }
    GRIDBAR();

    // ping-pong pointers (identical trajectory in every block)
    float* phiPrior = phiA;  float* phiS = phiB;
    float* hPhiOld  = hphiA; float* hPhiNew = hphiB;
    float* betaCur  = betaA; float* betaNxt = betaB;
    float* hbCur    = hbetaA; float* hbNxt  = hbetaB;

    // ======================= P1: phi0 GEMV + beta chain t=0 ==================
    if (bid < 252) {
        int gw = bid*8 + wid;            // 0..2015
        float am0 = a_m[l], am1 = a_m[64 + l];
        for (int r = gw; r < 262144; r += 2016) {
            const float* wr = W_s2phi + (size_t)r * 128;
            float v = am0*wr[l] + am1*wr[64 + l];
            #pragma unroll
            for (int m = 32; m >= 1; m >>= 1) v += __shfl_xor(v, m);
            if (l == 0) phiA[r] = v + b_s2phi[r];
        }
    } else {
        // beta0 rows rb0..rb0+3 into LDS Xl, then full beta step for t=0
        float* Xl = smem + 4096;
        float am0 = a_m[l], am1 = a_m[64 + l];
        for (int o = wid; o < 512; o += 8) {
            int go = rb0*128 + o;
            const float* wr = W_s2beta + (size_t)go * 128;
            float v = am0*wr[l] + am1*wr[64 + l];
            #pragma unroll
            for (int m = 32; m >= 1; m >>= 1) v += __shfl_xor(v, m);
            if (l == 0) Xl[o] = v + b_s2beta[go];
        }
        __syncthreads();
        beta_step(0, nullptr, nullptr, betaCur, hbCur);
    }
    GRIDBAR();

    // ======================= timestep loop ===================================
    #pragma unroll 1
    for (int t = 0; t < TT; ++t) {
        // ---- P23a: gru-phi. Block = 8 rows x all 768 gate-cols. ------------
        {
            const int R0 = bid * 8;
            const int jj = tid & 127;
            const int half = tid >> 8;         // 0: x-gates, 1: h-gates
            const int rr = (tid >> 7) & 1;     // rows rr*4 .. rr*4+3
            float aR[4] = {0,0,0,0}, aZ[4] = {0,0,0,0}, aN[4] = {0,0,0,0};
            float* Ws = smem;                  // [768][17]
            float* Xs = smem + 13056;          // [16][12]
            float* Hs = smem + 13248;          // [16][12]
            const float* Xg = phiPrior + (size_t)R0 * 128;
            const float* Hg = hPhiOld  + (size_t)R0 * 128;
            for (int k0 = 0; k0 < 128; k0 += 16) {
                #pragma unroll
                for (int ii = 0; ii < 6; ++ii) {
                    int s4 = tid + 512*ii;          // 0..3071
                    int row = s4 >> 2, k4 = (s4 & 3) * 4;
                    float4 wv = *(const float4*)(Bg_n + (size_t)row*128 + k0 + k4);
                    float* wp = Ws + row*17 + k4;
                    wp[0] = wv.x; wp[1] = wv.y; wp[2] = wv.z; wp[3] = wv.w;
                }
                if (tid < 256) {
                    int k = tid & 15, r = (tid >> 4) & 7;
                    bool isx = tid < 128;
                    float v = (isx ? Xg : Hg)[r*128 + k0 + k];
                    (isx ? Xs : Hs)[k*12 + r] = v;
                }
                __syncthreads();
                const float* vs = half ? Hs : Xs;
                const int wb0 = (half*384 + jj)*17;
                #pragma unroll
                for (int kk = 0; kk < 16; ++kk) {
                    float4 va = *(const float4*)(vs + kk*12 + rr*4);
                    float w0 = Ws[wb0 + kk];
                    float w1 = Ws[wb0 + 128*17 + kk];
                    float w2 = Ws[wb0 + 256*17 + kk];
                    aR[0] = fmaf(va.x, w0, aR[0]); aR[1] = fmaf(va.y, w0, aR[1]);
                    aR[2] = fmaf(va.z, w0, aR[2]); aR[3] = fmaf(va.w, w0, aR[3]);
                    aZ[0] = fmaf(va.x, w1, aZ[0]); aZ[1] = fmaf(va.y, w1, aZ[1]);
                    aZ[2] = fmaf(va.z, w1, aZ[2]); aZ[3] = fmaf(va.w, w1, aZ[3]);
                    aN[0] = fmaf(va.x, w2, aN[0]); aN[1] = fmaf(va.y, w2, aN[1]);
                    aN[2] = fmaf(va.z, w2, aN[2]); aN[3] = fmaf(va.w, w2, aN[3]);
                }
                __syncthreads();
            }
            float* hp = smem;                  // [3][8][128] (Ws dead)
            if (half == 1) {
                float b0 = bhh_n[jj], b1 = bhh_n[128+jj], b2 = bhh_n[256+jj];
                #pragma unroll
                for (int i = 0; i < 4; ++i) {
                    int row = rr*4 + i;
                    hp[(0*8 + row)*128 + jj] = aR[i] + b0;
                    hp[(1*8 + row)*128 + jj] = aZ[i] + b1;
                    hp[(2*8 + row)*128 + jj] = aN[i] + b2;
                }
            }
            __syncthreads();
            if (half == 0) {
                float b0 = bih_n[jj], b1 = bih_n[128+jj], b2 = bih_n[256+jj];
                #pragma unroll
                for (int i = 0; i < 4; ++i) {
                    int row = rr*4 + i;
                    float hr = hp[(0*8 + row)*128 + jj];
                    float hz = hp[(1*8 + row)*128 + jj];
                    float hn = hp[(2*8 + row)*128 + jj];
                    float r_ = sigmoidf_(aR[i] + b0 + hr);
                    float z_ = sigmoidf_(aZ[i] + b1 + hz);
                    float n_ = tanhf_   (aN[i] + b2 + r_*hn);
                    size_t gidx = (size_t)(R0 + row)*128 + jj;
                    float hold = hPhiOld[gidx];
                    hPhiNew[gidx] = (1.f - z_)*n_ + z_*hold;
                }
            }
        }
        __syncthreads();   // block-local dep only: gru(rows R0..R0+7) -> ms(same rows)

        // ---- P23b: mt + ms-phi (fused, no grid barrier needed) -------------
        {
            // mt: wave wid -> row n = bid*8 + wid
            {
                int n = bid*8 + wid;
                int k = l & 15, q = l >> 4;
                const float* bs = betaCur + k*128 + q*32;
                const float* wd = W_dec + (size_t)n*128 + q*32;
                float p = 0.f;
                #pragma unroll
                for (int t2 = 0; t2 < 32; ++t2) p = fmaf(bs[t2], wd[t2], p);
                p += __shfl_xor(p, 16);
                p += __shfl_xor(p, 32);
                if (l < 16) Mt[n*16 + l] = p * LOG2E;
            }
            // ms: block = 8 rows x 128 j x {mean,std}
            const int R0 = bid * 8;
            const int jj = tid & 127;
            const int q  = tid >> 7;          // 0..3
            const int grp = q >> 1;           // 0 mean, 1 std
            const int rr  = q & 1;            // rows rr*4..+3
            float a[4] = {0,0,0,0};
            float* Wms = smem;                // [256][17]
            float* Hs2 = smem + 4352;         // [16][12]
            const float* Hg = hPhiNew + (size_t)R0 * 128;
            for (int k0 = 0; k0 < 128; k0 += 16) {
                #pragma unroll
                for (int ii = 0; ii < 2; ++ii) {
                    int s4 = tid + 512*ii;        // 0..1023
                    int row = s4 >> 2, k4 = (s4 & 3) * 4;
                    float4 wv = *(const float4*)(Bms_n + (size_t)row*128 + k0 + k4);
                    float* wp = Wms + row*17 + k4;
                    wp[0] = wv.x; wp[1] = wv.y; wp[2] = wv.z; wp[3] = wv.w;
                }
                if (tid < 128) {
                    int k = tid & 15, r = (tid >> 4) & 7;
                    Hs2[k*12 + r] = Hg[r*128 + k0 + k];
                }
                __syncthreads();
                const int wb = (grp*128 + jj)*17;
                #pragma unroll
                for (int kk = 0; kk < 16; ++kk) {
                    float4 hv = *(const float4*)(Hs2 + kk*12 + rr*4);
                    float w = Wms[wb + kk];
                    a[0] = fmaf(hv.x, w, a[0]); a[1] = fmaf(hv.y, w, a[1]);
                    a[2] = fmaf(hv.z, w, a[2]); a[3] = fmaf(hv.w, w, a[3]);
                }
                __syncthreads();
            }
            float* msb = smem;                 // [2][8][128]
            float* red = smem + 2048;          // [8]
            {
                float bias = grp ? b_pstd[jj] : b_pmean[jj];
                #pragma unroll
                for (int i = 0; i < 4; ++i)
                    msb[(grp*8 + rr*4 + i)*128 + jj] = a[i] + bias;
            }
            __syncthreads();
            const float* epsP = eps_phi + (size_t)t * 262144;
            float kld = 0.f;
            #pragma unroll
            for (int ii = 0; ii < 2; ++ii) {
                int p2 = tid + 512*ii;
                int row = p2 >> 7, j2 = p2 & 127;
                float mean = msb[row*128 + j2];
                float stdv = softplusf_(msb[(8 + row)*128 + j2]);
                size_t gidx = (size_t)(R0 + row)*128 + j2;
                float outv = mean + stdv * epsP[gidx];
                phiS[gidx] = outv;
                float d = mean - phiPrior[gidx];
                kld += -logf_(stdv) + 0.5f*(stdv*stdv + d*d) - 0.5f;
            }
            #pragma unroll
            for (int m = 1; m < 64; m <<= 1) kld += __shfl_xor(kld, m);
            if (l == 0) red[wid] = kld;
            __syncthreads();
            if (tid == 0) {
                float s = 0.f;
                #pragma unroll
                for (int w2 = 0; w2 < 8; ++w2) s += red[w2];
                atomicAdd(accv + 4, s);
            }
        }
        GRIDBAR();   // B1: phiS/Mt -> all blocks

        // ---- P4: znll (+ hidden beta chain step t+1 on blocks 252..255) ----
        {
            if (bid >= 252) {
                if (t < TT - 1) beta_step(t + 1, betaCur, hbCur, betaNxt, hbNxt);
            }
            float* zbuf = smem;            // [64][16]
            float* ssb  = smem + 1024;     // [64][8]
            float* scb  = smem + 1536;     // [64][8]
            int*   cb   = (int*)(smem + 2048); // [64]
            float* kred = smem + 2112;     // [8]
            const int* edges_t = edges + (size_t)t * (EE*2);
            const float* u_t   = u_g   + (size_t)t * ((size_t)TWOE*KK);
            // phase 1: gumbel-softmax z + kld_z
            {
                int k = l >> 2, q = l & 3;
                int d0 = q * 32;
                const float4* wp = (const float4*)(W_pi    + k*128 + d0);
                const float4* bp = (const float4*)(betaCur + k*128 + d0);
                float4 wr0 = wp[0], wr1 = wp[1], wr2 = wp[2], wr3 = wp[3],
                       wr4 = wp[4], wr5 = wp[5], wr6 = wp[6], wr7 = wp[7];
                float4 br0 = bp[0], br1 = bp[1], br2 = bp[2], br3 = bp[3],
                       br4 = bp[4], br5 = bp[5], br6 = bp[6], br7 = bp[7];
                float kz = 0.f;
                #pragma unroll
                for (int it = 0; it < 8; ++it) {
                    int jl = wid * 8 + it;
                    int j = bid * 64 + jl;
                    int e = j & 8191; int fl = j >> 13;
                    int w = edges_t[e*2 + fl], c = edges_t[e*2 + (fl ^ 1)];
                    const float4* pw4 = (const float4*)(phiS + (size_t)w*128 + d0);
                    const float4* pc4 = (const float4*)(phiS + (size_t)c*128 + d0);
                    float lq = 0.f, lp = 0.f;
                    ZSTEP(pw4[0], pc4[0], wr0, br0); ZSTEP(pw4[1], pc4[1], wr1, br1);
                    ZSTEP(pw4[2], pc4[2], wr2, br2); ZSTEP(pw4[3], pc4[3], wr3, br3);
                    ZSTEP(pw4[4], pc4[4], wr4, br4); ZSTEP(pw4[5], pc4[5], wr5, br5);
                    ZSTEP(pw4[6], pc4[6], wr6, br6); ZSTEP(pw4[7], pc4[7], wr7, br7);
                    lq += __shfl_xor(lq, 1); lq += __shfl_xor(lq, 2);
                    lp += __shfl_xor(lp, 1); lp += __shfl_xor(lp, 2);
                    float eq = expf_(lq);
                    float sq = eq;
                    sq += __shfl_xor(sq, 4); sq += __shfl_xor(sq, 8);
                    sq += __shfl_xor(sq, 16); sq += __shfl_xor(sq, 32);
                    float logpost = lq - logf_(sq);
                    float post = eq * __builtin_amdgcn_rcpf(sq);
                    float mp = lp;
                    mp = fmaxf(mp, __shfl_xor(mp, 4));  mp = fmaxf(mp, __shfl_xor(mp, 8));
                    mp = fmaxf(mp, __shfl_xor(mp, 16)); mp = fmaxf(mp, __shfl_xor(mp, 32));
                    float ep = expf_(lp - mp);
                    float sp = ep;
                    sp += __shfl_xor(sp, 4); sp += __shfl_xor(sp, 8);
                    sp += __shfl_xor(sp, 16); sp += __shfl_xor(sp, 32);
                    float logprior = (lp - mp) - logf_(sp);
                    float v = post * (logpost - logprior);
                    v += __shfl_xor(v, 4); v += __shfl_xor(v, 8);
                    v += __shfl_xor(v, 16); v += __shfl_xor(v, 32);
                    kz += v;
                    float u = u_t[(size_t)j*16 + k];
                    float g = -logf_(-logf_(u + 1e-10f) + 1e-10f);
                    float zl = lq + g;
                    float ez = expf_(zl);
                    float sz = ez;
                    sz += __shfl_xor(sz, 4); sz += __shfl_xor(sz, 8);
                    sz += __shfl_xor(sz, 16); sz += __shfl_xor(sz, 32);
                    if (q == 0) zbuf[jl*16 + k] = ez * __builtin_amdgcn_rcpf(sz);
                    if (l == 0) cb[jl] = c;
                }
                if (l == 0) kred[wid] = kz;
            }
            __syncthreads();
            if (tid == 0) {
                float s = 0.f;
                #pragma unroll
                for (int w2 = 0; w2 < 8; ++w2) s += kred[w2];
                atomicAdd(accv + 1, s);
            }
            // phase 2: nll
            {
                int n0 = tid * 4;
                const float4* mp4 = (const float4*)(Mt + (size_t)n0 * 16);
                float4 M0 = mp4[0],  M1 = mp4[1],  M2  = mp4[2],  M3  = mp4[3];
                float4 M4 = mp4[4],  M5 = mp4[5],  M6  = mp4[6],  M7  = mp4[7];
                float4 M8 = mp4[8],  M9 = mp4[9],  M10 = mp4[10], M11 = mp4[11];
                float4 M12 = mp4[12], M13 = mp4[13], M14 = mp4[14], M15 = mp4[15];
                for (int e = 0; e < 64; ++e) {
                    const float4* zp = (const float4*)(zbuf + e*16);
                    float4 Z0 = zp[0], Z1 = zp[1], Z2 = zp[2], Z3 = zp[3];
                    int c = cb[e];
                    float v0 = D4(Z0, M0)  + D4(Z1, M1)  + D4(Z2, M2)  + D4(Z3, M3);
                    float v1 = D4(Z0, M4)  + D4(Z1, M5)  + D4(Z2, M6)  + D4(Z3, M7);
                    float v2 = D4(Z0, M8)  + D4(Z1, M9)  + D4(Z2, M10) + D4(Z3, M11);
                    float v3 = D4(Z0, M12) + D4(Z1, M13) + D4(Z2, M14) + D4(Z3, M15);
                    float s = exp2_(v0) + exp2_(v1) + exp2_(v2) + exp2_(v3);
                    float cv = 0.f;
                    cv = (c == n0    ) ? v0 : cv;
                    cv = (c == n0 + 1) ? v1 : cv;
                    cv = (c == n0 + 2) ? v2 : cv;
                    cv = (c == n0 + 3) ? v3 : cv;
                    #pragma unroll
                    for (int m = 1; m < 64; m <<= 1) {
                        s  += __shfl_xor(s, m);
                        cv += __shfl_xor(cv, m);
                    }
                    if (l == 0) { ssb[e*8 + wid] = s; scb[e*8 + wid] = cv; }
                }
                __syncthreads();
                if (tid < 64) {
                    float S = 0.f, CV = 0.f;
                    #pragma unroll
                    for (int w2 = 0; w2 < 8; ++w2) { S += ssb[tid*8 + w2]; CV += scb[tid*8 + w2]; }
                    float val = LN2 * (log2_(S) - CV);
                    #pragma unroll
                    for (int m = 1; m < 64; m <<= 1) val += __shfl_xor(val, m);
                    if (tid == 0) atomicAdd(accv + 0, val);
                }
            }
        }
        GRIDBAR();   // B2: betaNxt ready; Mt free to overwrite next t

        // swap ping-pong
        { float* tp = phiPrior; phiPrior = phiS;    phiS = tp; }
        { float* th = hPhiOld;  hPhiOld  = hPhiNew; hPhiNew = th; }
        { float* tb = betaCur;  betaCur  = betaNxt; betaNxt = tb; }
        { float* tb = hbCur;    hbCur    = hbNxt;   hbNxt = tb; }
    }

    // ======================= final output ====================================
    if (bid == 0 && tid == 0) {
        out[0] = accv[0] / CNT;
        out[1] = accv[1] / CNT;
        out[2] = 16.f * accv[2] / CNT;
        out[3] = accv[3] / CNT;
        out[4] = accv[4] / CNT;
    }
#undef GRIDBAR
}

// ---------------------------------------------------------------------------
extern "C" void kernel_launch(void* const* d_in, const int* in_sizes, int n_in,
                              void* d_out, int out_size, void* d_ws, size_t ws_size,
                              hipStream_t stream)
{
    (void)in_sizes; (void)n_in; (void)out_size; (void)ws_size;
    const int*   edges   = (const int*)d_in[0];
    const int*   sidx    = (const int*)d_in[1];
    const float* eps_phi = (const float*)d_in[2];
    const float* eps_beta= (const float*)d_in[3];
    const float* u_g     = (const float*)d_in[4];
    const float* amE     = (const float*)d_in[5];
    const float* asE     = (const float*)d_in[6];
    const float* W_s2phi = (const float*)d_in[7];
    const float* b_s2phi = (const float*)d_in[8];
    const float* W_s2beta= (const float*)d_in[9];
    const float* b_s2beta= (const float*)d_in[10];
    const float* W_bmean = (const float*)d_in[11];
    const float* b_bmean = (const float*)d_in[12];
    const float* W_bstd  = (const float*)d_in[13];
    const float* b_bstd  = (const float*)d_in[14];
    const float* W_pmean = (const float*)d_in[15];
    const float* b_pmean = (const float*)d_in[16];
    const float* W_pstd  = (const float*)d_in[17];
    const float* b_pstd  = (const float*)d_in[18];
    const float* W_pi    = (const float*)d_in[19];
    const float* Wih_n   = (const float*)d_in[20];
    const float* Whh_n   = (const float*)d_in[21];
    const float* bih_n   = (const float*)d_in[22];
    const float* bhh_n   = (const float*)d_in[23];
    const float* Wih_c   = (const float*)d_in[24];
    const float* Whh_c   = (const float*)d_in[25];
    const float* bih_c   = (const float*)d_in[26];
    const float* bhh_c   = (const float*)d_in[27];
    const float* W_dec   = (const float*)d_in[28];

    float* ws     = (float*)d_ws;
    float* Bg_n   = ws;                    // 98304
    float* Bg_c   = Bg_n   + 98304;        // 98304 (k-major [128][768])
    float* Bms_n  = Bg_c   + 98304;        // 32768
    float* Bms_c  = Bms_n  + 32768;        // 32768 (k-major [128][256])
    float* a_m    = Bms_c  + 32768;        // 128
    float* phiA   = a_m    + 128;          // 262144
    float* phiB   = phiA   + 262144;       // 262144
    float* hphiA  = phiB   + 262144;       // 262144
    float* hphiB  = hphiA  + 262144;       // 262144
    float* betaA  = hphiB  + 262144;       // 2048
    float* betaB  = betaA  + 2048;         // 2048
    float* hbetaA = betaB  + 2048;         // 2048
    float* hbetaB = hbetaA + 2048;         // 2048
    float* Mt     = hbetaB + 2048;         // 32768
    float* acc    = Mt     + 32768;        // 8 (acc[7] = grid barrier counter)

    zero_cnt_kernel<<<1, 64, 0, stream>>>((unsigned*)(acc + 7));
    mega_kernel<<<NBLK, NTHR, 0, stream>>>(
        edges, sidx, eps_phi, eps_beta, u_g, amE, asE,
        W_s2phi, b_s2phi, W_s2beta, b_s2beta,
        W_bmean, b_bmean, W_bstd, b_bstd,
        W_pmean, b_pmean, W_pstd, b_pstd,
        W_pi, Wih_n, Whh_n, bih_n, bhh_n, Wih_c, Whh_c, bih_c, bhh_c, W_dec,
        Bg_n, Bg_c, Bms_n, Bms_c, a_m,
        phiA, phiB, hphiA, hphiB, betaA, betaB, hbetaA, hbetaB,
        Mt, acc, (float*)d_out);
}